// Round 1
// baseline (42.057 us; speedup 1.0000x reference)
//
#include <hip/hip_runtime.h>

#define B_ 8
#define N_ 256
#define D_ 128
#define TI 8   // output rows per block in reduce kernel

// K1: A[r][f] = sum_d x[r][d]*W[d][f] + bias[f];  C[r][f] = sum_d x[r][d]*W[D+d][f]
// r = b*N + n flattened row. 256 threads: tid<128 -> A, tid>=128 -> C.
__global__ __launch_bounds__(256) void gemm_ac_kernel(
    const float* __restrict__ x, const float* __restrict__ W,
    const float* __restrict__ bias, float* __restrict__ A, float* __restrict__ C) {
    const int r   = blockIdx.x;          // 0 .. B*N-1
    const int tid = threadIdx.x;         // 0 .. 255
    const int f   = tid & (D_ - 1);
    const bool isC = tid >= D_;
    const float* __restrict__ Wp = W + (isC ? D_ * D_ : 0) + f;
    const float* __restrict__ xr = x + (size_t)r * D_;   // block-uniform -> scalar loads
    float acc = 0.0f;
    #pragma unroll 8
    for (int d = 0; d < D_; ++d) {
        acc += xr[d] * Wp[d * D_];
    }
    if (isC) C[(size_t)r * D_ + f] = acc;
    else     A[(size_t)r * D_ + f] = acc + bias[f];
}

// K2: out[b,i,f] = sum_j relu(A'[b,i,f] + C[b,j,f])   (A' already has bias folded)
// One block per (b, 8-row tile). 128 threads, one per f.
__global__ __launch_bounds__(128) void reduce_edges_kernel(
    const float* __restrict__ A, const float* __restrict__ C,
    float* __restrict__ out) {
    const int blk = blockIdx.x;                  // 0 .. B*N/TI - 1
    const int b   = blk / (N_ / TI);
    const int i0  = (blk % (N_ / TI)) * TI;
    const int f   = threadIdx.x;
    const size_t base = ((size_t)b * N_ + i0) * D_ + f;

    float a[TI], acc[TI];
    #pragma unroll
    for (int k = 0; k < TI; ++k) { a[k] = A[base + (size_t)k * D_]; acc[k] = 0.0f; }

    const float* __restrict__ Cb = C + (size_t)b * N_ * D_ + f;
    #pragma unroll 4
    for (int j = 0; j < N_; ++j) {
        const float cv = Cb[(size_t)j * D_];
        #pragma unroll
        for (int k = 0; k < TI; ++k) acc[k] += fmaxf(a[k] + cv, 0.0f);
    }
    #pragma unroll
    for (int k = 0; k < TI; ++k) out[base + (size_t)k * D_] = acc[k];
}

// Fallback (only if workspace too small): fully fused, recomputes C per row.
__global__ __launch_bounds__(128) void fused_naive_kernel(
    const float* __restrict__ x, const float* __restrict__ W,
    const float* __restrict__ bias, float* __restrict__ out) {
    const int r = blockIdx.x;          // b*N + i
    const int b = r / N_;
    const int f = threadIdx.x;
    const float* __restrict__ xi = x + (size_t)r * D_;
    float a = bias[f];
    for (int d = 0; d < D_; ++d) a += xi[d] * W[d * D_ + f];
    float acc = 0.0f;
    const float* __restrict__ xb = x + (size_t)b * N_ * D_;
    for (int j = 0; j < N_; ++j) {
        const float* __restrict__ xj = xb + (size_t)j * D_;
        float c = 0.0f;
        for (int d = 0; d < D_; ++d) c += xj[d] * W[(D_ + d) * D_ + f];
        acc += fmaxf(a + c, 0.0f);
    }
    out[(size_t)r * D_ + f] = acc;
}

extern "C" void kernel_launch(void* const* d_in, const int* in_sizes, int n_in,
                              void* d_out, int out_size, void* d_ws, size_t ws_size,
                              hipStream_t stream) {
    const float* x    = (const float*)d_in[0];   // (B, N, D) fp32
    const float* W    = (const float*)d_in[1];   // (2D, D)   fp32
    const float* bias = (const float*)d_in[2];   // (D,)      fp32
    float* out = (float*)d_out;                  // (B, N, D) fp32

    const size_t elems = (size_t)B_ * N_ * D_;
    const size_t need  = 2 * elems * sizeof(float);

    if (ws_size >= need) {
        float* A = (float*)d_ws;
        float* C = A + elems;
        gemm_ac_kernel<<<B_ * N_, 256, 0, stream>>>(x, W, bias, A, C);
        reduce_edges_kernel<<<(B_ * N_) / TI, D_, 0, stream>>>(A, C, out);
    } else {
        fused_naive_kernel<<<B_ * N_, D_, 0, stream>>>(x, W, bias, out);
    }
}

// Round 2
// 19.271 us; speedup vs baseline: 2.1824x; 2.1824x over previous
//
#include <hip/hip_runtime.h>

#define B_ 8
#define N_ 256
#define D_ 128

// ---------------------------------------------------------------------------
// K1: A[r][f] = sum_d x[r][d]*W[d][f] + bias[f];  C[r][f] = sum_d x[r][d]*W[D+d][f]
// 256 blocks x 8 rows; 256 threads. W staged through LDS in 32-row chunks so
// every W element is fetched from L2 exactly once per block (33 MB chip-wide).
// Thread (rq,cq): rows {rq*2, rq*2+1}, cols cq*4..+3 of the 256 concat cols.
// ---------------------------------------------------------------------------
__global__ __launch_bounds__(256) void gemm_ac_kernel(
    const float* __restrict__ x, const float* __restrict__ W,
    const float* __restrict__ bias, float* __restrict__ A, float* __restrict__ C) {
    __shared__ float  xs[8][D_];    // 4 KB
    __shared__ float4 Ws[32][64];   // 32 KB: 32 d-rows x 256 concat cols

    const int tid  = threadIdx.x;
    const int r0   = blockIdx.x * 8;
    const int rq   = tid >> 6;      // 0..3
    const int cq   = tid & 63;      // 0..63 -> cols cq*4..+3
    const int halfC = cq >> 5;      // 0: A-half, 1: C-half
    const int f    = (cq * 4) & 127;

    // stage x tile (8 rows x 128)
    {
        const int row = tid >> 5;   // 0..7
        const int dq  = tid & 31;   // 0..31
        reinterpret_cast<float4*>(&xs[row][0])[dq] =
            *reinterpret_cast<const float4*>(x + (size_t)(r0 + row) * D_ + dq * 4);
    }

    float4 acc0 = make_float4(0.f, 0.f, 0.f, 0.f);
    float4 acc1 = make_float4(0.f, 0.f, 0.f, 0.f);

    for (int chunk = 0; chunk < 4; ++chunk) {
        if (chunk) __syncthreads();
        // cooperative W stage: 2048 float4 per chunk, 8 per thread
        #pragma unroll
        for (int k = 0; k < 8; ++k) {
            const int id = k * 256 + tid;
            const int dd = id >> 6;          // 0..31
            const int cg = id & 63;          // 0..63
            const int srow = chunk * 32 + dd + ((cg >> 5) << 7);  // +128 for C-half
            Ws[dd][cg] = *reinterpret_cast<const float4*>(
                W + (size_t)srow * D_ + (cg & 31) * 4);
        }
        __syncthreads();

        const int dbase = chunk * 32;
        #pragma unroll
        for (int dd = 0; dd < 32; ++dd) {
            const float4 wv = Ws[dd][cq];
            const float x0 = xs[rq * 2    ][dbase + dd];
            const float x1 = xs[rq * 2 + 1][dbase + dd];
            acc0.x += x0 * wv.x; acc0.y += x0 * wv.y;
            acc0.z += x0 * wv.z; acc0.w += x0 * wv.w;
            acc1.x += x1 * wv.x; acc1.y += x1 * wv.y;
            acc1.z += x1 * wv.z; acc1.w += x1 * wv.w;
        }
    }

    const int row0 = r0 + rq * 2;
    if (halfC) {
        *reinterpret_cast<float4*>(C + (size_t)row0 * D_ + f)       = acc0;
        *reinterpret_cast<float4*>(C + (size_t)(row0 + 1) * D_ + f) = acc1;
    } else {
        const float4 bv = *reinterpret_cast<const float4*>(bias + f);
        acc0.x += bv.x; acc0.y += bv.y; acc0.z += bv.z; acc0.w += bv.w;
        acc1.x += bv.x; acc1.y += bv.y; acc1.z += bv.z; acc1.w += bv.w;
        *reinterpret_cast<float4*>(A + (size_t)row0 * D_ + f)       = acc0;
        *reinterpret_cast<float4*>(A + (size_t)(row0 + 1) * D_ + f) = acc1;
    }
}

// ---------------------------------------------------------------------------
// K2: out[b,i,f] = sum_j relu(A'[b,i,f] + C[b,j,f])
// 512 blocks x 4 rows; 512 threads = 32 f-groups (float4) x 16 j-groups.
// Each j-group handles 16 j's; log2 LDS tree-reduce over the 16 partials.
// ---------------------------------------------------------------------------
__global__ __launch_bounds__(512) void reduce_edges_kernel(
    const float* __restrict__ A, const float* __restrict__ C,
    float* __restrict__ out) {
    __shared__ float4 part[8][4][32];   // 16 KB

    const int blk = blockIdx.x;          // 0..511
    const int b   = blk >> 6;            // N/TI = 64 blocks per batch
    const int i0  = (blk & 63) * 4;
    const int tid = threadIdx.x;
    const int fq  = tid & 31;            // float4 group: f = fq*4
    const int jg  = tid >> 5;            // 0..15
    const int f   = fq * 4;

    float4 av[4], acc[4];
    #pragma unroll
    for (int r = 0; r < 4; ++r) {
        av[r] = *reinterpret_cast<const float4*>(
            A + ((size_t)(b * N_ + i0 + r)) * D_ + f);
        acc[r] = make_float4(0.f, 0.f, 0.f, 0.f);
    }

    const float* __restrict__ Cb = C + (size_t)b * N_ * D_ + f;
    #pragma unroll 4
    for (int jj = 0; jj < 16; ++jj) {
        const int j = jg * 16 + jj;
        const float4 cv = *reinterpret_cast<const float4*>(Cb + (size_t)j * D_);
        #pragma unroll
        for (int r = 0; r < 4; ++r) {
            acc[r].x += fmaxf(av[r].x + cv.x, 0.f);
            acc[r].y += fmaxf(av[r].y + cv.y, 0.f);
            acc[r].z += fmaxf(av[r].z + cv.z, 0.f);
            acc[r].w += fmaxf(av[r].w + cv.w, 0.f);
        }
    }

    // tree reduction over the 16 j-groups
    #pragma unroll
    for (int s = 8; s >= 1; s >>= 1) {
        if (jg >= s && jg < 2 * s) {
            #pragma unroll
            for (int r = 0; r < 4; ++r) part[jg - s][r][fq] = acc[r];
        }
        __syncthreads();
        if (jg < s) {
            #pragma unroll
            for (int r = 0; r < 4; ++r) {
                const float4 p = part[jg][r][fq];
                acc[r].x += p.x; acc[r].y += p.y;
                acc[r].z += p.z; acc[r].w += p.w;
            }
        }
        __syncthreads();
    }

    if (jg == 0) {
        #pragma unroll
        for (int r = 0; r < 4; ++r) {
            *reinterpret_cast<float4*>(
                out + ((size_t)(b * N_ + i0 + r)) * D_ + f) = acc[r];
        }
    }
}

// Fallback (only if workspace too small): fully fused, recomputes C per row.
__global__ __launch_bounds__(128) void fused_naive_kernel(
    const float* __restrict__ x, const float* __restrict__ W,
    const float* __restrict__ bias, float* __restrict__ out) {
    const int r = blockIdx.x;
    const int b = r / N_;
    const int f = threadIdx.x;
    const float* __restrict__ xi = x + (size_t)r * D_;
    float a = bias[f];
    for (int d = 0; d < D_; ++d) a += xi[d] * W[d * D_ + f];
    float acc = 0.0f;
    const float* __restrict__ xb = x + (size_t)b * N_ * D_;
    for (int j = 0; j < N_; ++j) {
        const float* __restrict__ xj = xb + (size_t)j * D_;
        float c = 0.0f;
        for (int d = 0; d < D_; ++d) c += xj[d] * W[(D_ + d) * D_ + f];
        acc += fmaxf(a + c, 0.0f);
    }
    out[(size_t)r * D_ + f] = acc;
}

extern "C" void kernel_launch(void* const* d_in, const int* in_sizes, int n_in,
                              void* d_out, int out_size, void* d_ws, size_t ws_size,
                              hipStream_t stream) {
    const float* x    = (const float*)d_in[0];   // (B, N, D) fp32
    const float* W    = (const float*)d_in[1];   // (2D, D)   fp32
    const float* bias = (const float*)d_in[2];   // (D,)      fp32
    float* out = (float*)d_out;                  // (B, N, D) fp32

    const size_t elems = (size_t)B_ * N_ * D_;
    const size_t need  = 2 * elems * sizeof(float);

    if (ws_size >= need) {
        float* A = (float*)d_ws;
        float* C = A + elems;
        gemm_ac_kernel<<<(B_ * N_) / 8, 256, 0, stream>>>(x, W, bias, A, C);
        reduce_edges_kernel<<<(B_ * N_) / 4, 512, 0, stream>>>(A, C, out);
    } else {
        fused_naive_kernel<<<B_ * N_, D_, 0, stream>>>(x, W, bias, out);
    }
}